// Round 13
// baseline (200.797 us; speedup 1.0000x reference)
//
#include <hip/hip_runtime.h>

#define LSTREAM 512
#define C 8
#define OUTD 584    // 8 + 64 + 512
#define NW 16       // waves per block
#define SEG 32      // steps per wave (wave 15's step 511 is an exact no-op)
#define TSTRIDE 516 // incT column stride in f32 (4i mod 32 banks -> conflict-free)
#define PSTRIDE 600 // partial-signature stride in floats

typedef __attribute__((ext_vector_type(8))) _Float16 h16x8;
typedef __attribute__((ext_vector_type(4))) _Float16 h16x4;

// Chen combine: state (a, in regs) <- a (x) b (in LDS at bp). a is earlier.
// Lane = i*8+j owns a2[i][j] (s2), a3[i][j][0..7] (s3); s1i = a1[i].
__device__ __forceinline__ void chen_combine(const float* bp, int i, int j, int lane,
                                             float& s1i, float& s2, float (&s3)[C]) {
    const float  b1i  = bp[i];
    const float  b1j  = bp[j];
    const float4 b1lo = *reinterpret_cast<const float4*>(bp);
    const float4 b1hi = *reinterpret_cast<const float4*>(bp + 4);
    const float4 b2lo = *reinterpret_cast<const float4*>(bp + C + j * C);
    const float4 b2hi = *reinterpret_cast<const float4*>(bp + C + j * C + 4);
    const float  b2ij = bp[C + lane];
    const float4 b3lo = *reinterpret_cast<const float4*>(bp + C + 64 + lane * C);
    const float4 b3hi = *reinterpret_cast<const float4*>(bp + C + 64 + lane * C + 4);
    const float b1k[C]  = {b1lo.x, b1lo.y, b1lo.z, b1lo.w, b1hi.x, b1hi.y, b1hi.z, b1hi.w};
    const float b2jk[C] = {b2lo.x, b2lo.y, b2lo.z, b2lo.w, b2hi.x, b2hi.y, b2hi.z, b2hi.w};
    const float b3k[C]  = {b3lo.x, b3lo.y, b3lo.z, b3lo.w, b3hi.x, b3hi.y, b3hi.z, b3hi.w};
    #pragma unroll
    for (int k = 0; k < C; ++k)
        s3[k] = s3[k] + b3k[k] + s1i * b2jk[k] + s2 * b1k[k];
    s2 = s2 + b2ij + s1i * b1j;
    s1i += b1i;
}

__device__ __forceinline__ void store_partial(float* pp, int i, int j, int lane,
                                              float s1i, float s2, const float (&s3)[C]) {
    if (j == 0) pp[i] = s1i;
    pp[C + lane] = s2;
    #pragma unroll
    for (int k = 0; k < C; ++k) pp[C + 64 + lane * C + k] = s3[k];
}

__global__ __launch_bounds__(1024, 8) void sig_kernel(const float* __restrict__ path,
                                                      float* __restrict__ out) {
    __shared__ float    incT[C * TSTRIDE];      // 16.5 KB: transposed f32 increments [c][t]
    __shared__ _Float16 inc_h[LSTREAM * C];     //  8.0 KB: fp16 increment rows [t][c]
    __shared__ float    part[NW * PSTRIDE];     // 37.5 KB: per-wave partials
    const int b    = blockIdx.x;
    const int tid  = threadIdx.x;
    const int wu   = tid >> 6;
    const int lane = tid & 63;
    const int i = lane >> 3;
    const int j = lane & 7;

    const float* pb = path + (size_t)b * (LSTREAM * C);

    // ---- pre-pass: increments -> (a) transposed f32, (b) row-major fp16; row 511 = 0 ----
    {
        const int row = tid >> 1, h = tid & 1;
        float4 d = {0.f, 0.f, 0.f, 0.f};
        if (row < LSTREAM - 1) {
            const float4* p4 = reinterpret_cast<const float4*>(pb);
            const float4 a = p4[tid];       // (row, half h)
            const float4 c = p4[tid + 2];   // (row+1, half h)
            d.x = c.x - a.x; d.y = c.y - a.y; d.z = c.z - a.z; d.w = c.w - a.w;
        }
        // transposed f32 (per-instr: banks 16h+4c+row -> exactly 2 lanes/bank = free)
        incT[(4 * h + 0) * TSTRIDE + row] = d.x;
        incT[(4 * h + 1) * TSTRIDE + row] = d.y;
        incT[(4 * h + 2) * TSTRIDE + row] = d.z;
        incT[(4 * h + 3) * TSTRIDE + row] = d.w;
        // fp16 half-row (8B write, 2-way bank aliasing = free)
        h16x4 hv;
        hv[0] = (_Float16)d.x; hv[1] = (_Float16)d.y;
        hv[2] = (_Float16)d.z; hv[3] = (_Float16)d.w;
        *reinterpret_cast<h16x4*>(inc_h + row * C + h * 4) = hv;
    }
    __syncthreads();

    const int r0 = wu * SEG;
    const float* ti = incT + i * TSTRIDE + r0;  // dxi pairs: 1 ds_read_b64 per 2 steps
    const float* tj = incT + j * TSTRIDE + r0;
    const h16x8* hr = reinterpret_cast<const h16x8*>(inc_h) + r0;  // 1 b128 = full dx row

    float s1i = 0.f, s2 = 0.f;
    float s3[C];
    #pragma unroll
    for (int k = 0; k < C; ++k) s3[k] = 0.f;

    #pragma unroll
    for (int m = 0; m < SEG / 2; ++m) {
        const float2 qi = *reinterpret_cast<const float2*>(ti + 2 * m);
        const float2 qj = *reinterpret_cast<const float2*>(tj + 2 * m);
        const h16x8 ra = hr[2 * m];
        const h16x8 rb = hr[2 * m + 1];
        // ---- step 2m ----
        {
            const float dxi = qi.x, dxj = qj.x;
            const float u  = dxi * dxj;
            const float t1 = s1i * dxj;
            const float cf = fmaf(u, (1.f / 6.f), fmaf(t1, 0.5f, s2));
            #pragma unroll
            for (int k = 0; k < C; ++k) s3[k] = fmaf(cf, (float)ra[k], s3[k]);
            s2 = fmaf(u, 0.5f, s2) + t1;
            s1i += dxi;
        }
        // ---- step 2m+1 ----
        {
            const float dxi = qi.y, dxj = qj.y;
            const float u  = dxi * dxj;
            const float t1 = s1i * dxj;
            const float cf = fmaf(u, (1.f / 6.f), fmaf(t1, 0.5f, s2));
            #pragma unroll
            for (int k = 0; k < C; ++k) s3[k] = fmaf(cf, (float)rb[k], s3[k]);
            s2 = fmaf(u, 0.5f, s2) + t1;
            s1i += dxi;
        }
    }

    // ---- publish partials, tree-combine 16 -> 1 ----
    store_partial(part + wu * PSTRIDE, i, j, lane, s1i, s2, s3);
    __syncthreads();

    if ((wu & 1) == 0) chen_combine(part + (wu + 1) * PSTRIDE, i, j, lane, s1i, s2, s3);
    if (wu == 2 || wu == 6 || wu == 10 || wu == 14)
        store_partial(part + wu * PSTRIDE, i, j, lane, s1i, s2, s3);
    __syncthreads();

    if ((wu & 3) == 0) chen_combine(part + (wu + 2) * PSTRIDE, i, j, lane, s1i, s2, s3);
    if (wu == 4 || wu == 12)
        store_partial(part + wu * PSTRIDE, i, j, lane, s1i, s2, s3);
    __syncthreads();

    if ((wu & 7) == 0) chen_combine(part + (wu + 4) * PSTRIDE, i, j, lane, s1i, s2, s3);
    if (wu == 8)
        store_partial(part + wu * PSTRIDE, i, j, lane, s1i, s2, s3);
    __syncthreads();

    if (wu == 0) {
        chen_combine(part + 8 * PSTRIDE, i, j, lane, s1i, s2, s3);
        float* ob = out + (size_t)b * OUTD;
        const float s1out = __shfl(s1i, (lane << 3) & 63, 64);
        if (lane < C) ob[lane] = s1out;
        ob[C + lane] = s2;
        #pragma unroll
        for (int k = 0; k < C; ++k) ob[C + 64 + lane * C + k] = s3[k];
    }
}

extern "C" void kernel_launch(void* const* d_in, const int* in_sizes, int n_in,
                              void* d_out, int out_size, void* d_ws, size_t ws_size,
                              hipStream_t stream) {
    const float* path = (const float*)d_in[0];
    float* out = (float*)d_out;
    const int B = in_sizes[0] / (LSTREAM * C);
    sig_kernel<<<B, 1024, 0, stream>>>(path, out);
}

// Round 14
// 17.560 us; speedup vs baseline: 11.4350x; 11.4350x over previous
//
#include <hip/hip_runtime.h>

#define LSTREAM 512
#define C 8
#define OUTD 584    // 8 + 64 + 512
#define NW 16       // waves per block
#define SEG 32      // steps per wave (wave 15's step 511 is an exact no-op)
#define TSTRIDE 516 // incT column stride in f32 (4i mod 32 banks -> conflict-free)
#define PSTRIDE 600 // partial-signature stride in floats

typedef __attribute__((ext_vector_type(8))) _Float16 h16x8;
typedef __attribute__((ext_vector_type(4))) _Float16 h16x4;

// Chen combine: state (a, in regs) <- a (x) b (in LDS at bp). a is earlier.
// Lane = i*8+j owns a2[i][j] (s2), a3[i][j][0..7] (s3); s1i = a1[i].
__device__ __forceinline__ void chen_combine(const float* bp, int i, int j, int lane,
                                             float& s1i, float& s2, float (&s3)[C]) {
    const float  b1i  = bp[i];
    const float  b1j  = bp[j];
    const float4 b1lo = *reinterpret_cast<const float4*>(bp);
    const float4 b1hi = *reinterpret_cast<const float4*>(bp + 4);
    const float4 b2lo = *reinterpret_cast<const float4*>(bp + C + j * C);
    const float4 b2hi = *reinterpret_cast<const float4*>(bp + C + j * C + 4);
    const float  b2ij = bp[C + lane];
    const float4 b3lo = *reinterpret_cast<const float4*>(bp + C + 64 + lane * C);
    const float4 b3hi = *reinterpret_cast<const float4*>(bp + C + 64 + lane * C + 4);
    const float b1k[C]  = {b1lo.x, b1lo.y, b1lo.z, b1lo.w, b1hi.x, b1hi.y, b1hi.z, b1hi.w};
    const float b2jk[C] = {b2lo.x, b2lo.y, b2lo.z, b2lo.w, b2hi.x, b2hi.y, b2hi.z, b2hi.w};
    const float b3k[C]  = {b3lo.x, b3lo.y, b3lo.z, b3lo.w, b3hi.x, b3hi.y, b3hi.z, b3hi.w};
    #pragma unroll
    for (int k = 0; k < C; ++k)
        s3[k] = s3[k] + b3k[k] + s1i * b2jk[k] + s2 * b1k[k];
    s2 = s2 + b2ij + s1i * b1j;
    s1i += b1i;
}

__device__ __forceinline__ void store_partial(float* pp, int i, int j, int lane,
                                              float s1i, float s2, const float (&s3)[C]) {
    if (j == 0) pp[i] = s1i;
    pp[C + lane] = s2;
    #pragma unroll
    for (int k = 0; k < C; ++k) pp[C + 64 + lane * C + k] = s3[k];
}

__global__ __launch_bounds__(1024, 8) void sig_kernel(const float* __restrict__ path,
                                                      float* __restrict__ out) {
    __shared__ float    incT[C * TSTRIDE];      // 16.5 KB: transposed f32 increments [c][t]
    __shared__ _Float16 inc_h[LSTREAM * C];     //  8.0 KB: fp16 increment rows [t][c]
    __shared__ float    part[NW * PSTRIDE];     // 37.5 KB: per-wave partials
    const int b    = blockIdx.x;
    const int tid  = threadIdx.x;
    const int wu   = tid >> 6;
    const int lane = tid & 63;
    const int i = lane >> 3;
    const int j = lane & 7;

    const float* pb = path + (size_t)b * (LSTREAM * C);

    // ---- pre-pass: increments -> (a) transposed f32, (b) row-major fp16; row 511 = 0 ----
    {
        const int row = tid >> 1, h = tid & 1;
        float4 d = {0.f, 0.f, 0.f, 0.f};
        if (row < LSTREAM - 1) {
            const float4* p4 = reinterpret_cast<const float4*>(pb);
            const float4 a = p4[tid];       // (row, half h)
            const float4 c = p4[tid + 2];   // (row+1, half h)
            d.x = c.x - a.x; d.y = c.y - a.y; d.z = c.z - a.z; d.w = c.w - a.w;
        }
        // transposed f32 (per-instr: banks 16h+4c+row -> exactly 2 lanes/bank = free)
        incT[(4 * h + 0) * TSTRIDE + row] = d.x;
        incT[(4 * h + 1) * TSTRIDE + row] = d.y;
        incT[(4 * h + 2) * TSTRIDE + row] = d.z;
        incT[(4 * h + 3) * TSTRIDE + row] = d.w;
        // fp16 half-row (8B write, 2-way bank aliasing = free)
        h16x4 hv;
        hv[0] = (_Float16)d.x; hv[1] = (_Float16)d.y;
        hv[2] = (_Float16)d.z; hv[3] = (_Float16)d.w;
        *reinterpret_cast<h16x4*>(inc_h + row * C + h * 4) = hv;
    }
    __syncthreads();

    const int r0 = wu * SEG;
    const float* ti = incT + i * TSTRIDE + r0;  // dxi pairs: 1 ds_read_b64 per 2 steps
    const float* tj = incT + j * TSTRIDE + r0;
    const h16x8* hr = reinterpret_cast<const h16x8*>(inc_h) + r0;  // 1 b128 = full dx row

    float s1i = 0.f, s2 = 0.f;
    float s3[C];
    #pragma unroll
    for (int k = 0; k < C; ++k) s3[k] = 0.f;

    // partial unroll ONLY (anti-spill: full unroll batches 64 LDS loads and
    // spills under the 64-VGPR cap -- R5/R7/R13 all died of this)
    #pragma unroll 2
    for (int m = 0; m < SEG / 2; ++m) {
        const float2 qi = *reinterpret_cast<const float2*>(ti + 2 * m);
        const float2 qj = *reinterpret_cast<const float2*>(tj + 2 * m);
        const h16x8 ra = hr[2 * m];
        const h16x8 rb = hr[2 * m + 1];
        // ---- step 2m ----
        {
            const float dxi = qi.x, dxj = qj.x;
            const float u  = dxi * dxj;
            const float t1 = s1i * dxj;
            const float cf = fmaf(u, (1.f / 6.f), fmaf(t1, 0.5f, s2));
            #pragma unroll
            for (int k = 0; k < C; ++k) s3[k] = fmaf(cf, (float)ra[k], s3[k]);
            s2 = fmaf(u, 0.5f, s2) + t1;
            s1i += dxi;
        }
        // ---- step 2m+1 ----
        {
            const float dxi = qi.y, dxj = qj.y;
            const float u  = dxi * dxj;
            const float t1 = s1i * dxj;
            const float cf = fmaf(u, (1.f / 6.f), fmaf(t1, 0.5f, s2));
            #pragma unroll
            for (int k = 0; k < C; ++k) s3[k] = fmaf(cf, (float)rb[k], s3[k]);
            s2 = fmaf(u, 0.5f, s2) + t1;
            s1i += dxi;
        }
    }

    // ---- publish partials, tree-combine 16 -> 1 ----
    store_partial(part + wu * PSTRIDE, i, j, lane, s1i, s2, s3);
    __syncthreads();

    if ((wu & 1) == 0) chen_combine(part + (wu + 1) * PSTRIDE, i, j, lane, s1i, s2, s3);
    if (wu == 2 || wu == 6 || wu == 10 || wu == 14)
        store_partial(part + wu * PSTRIDE, i, j, lane, s1i, s2, s3);
    __syncthreads();

    if ((wu & 3) == 0) chen_combine(part + (wu + 2) * PSTRIDE, i, j, lane, s1i, s2, s3);
    if (wu == 4 || wu == 12)
        store_partial(part + wu * PSTRIDE, i, j, lane, s1i, s2, s3);
    __syncthreads();

    if ((wu & 7) == 0) chen_combine(part + (wu + 4) * PSTRIDE, i, j, lane, s1i, s2, s3);
    if (wu == 8)
        store_partial(part + wu * PSTRIDE, i, j, lane, s1i, s2, s3);
    __syncthreads();

    if (wu == 0) {
        chen_combine(part + 8 * PSTRIDE, i, j, lane, s1i, s2, s3);
        float* ob = out + (size_t)b * OUTD;
        const float s1out = __shfl(s1i, (lane << 3) & 63, 64);
        if (lane < C) ob[lane] = s1out;
        ob[C + lane] = s2;
        #pragma unroll
        for (int k = 0; k < C; ++k) ob[C + 64 + lane * C + k] = s3[k];
    }
}

extern "C" void kernel_launch(void* const* d_in, const int* in_sizes, int n_in,
                              void* d_out, int out_size, void* d_ws, size_t ws_size,
                              hipStream_t stream) {
    const float* path = (const float*)d_in[0];
    float* out = (float*)d_out;
    const int B = in_sizes[0] / (LSTREAM * C);
    sig_kernel<<<B, 1024, 0, stream>>>(path, out);
}